// Round 1
// baseline (2799.353 us; speedup 1.0000x reference)
//
#include <hip/hip_runtime.h>
#include <cstddef>

// LinearAttention (Performer-style fourier features), fp32 baseline.
// B=4 L=4096 D_MODEL=1024 H=16 d_head=64 d_kmap=128 (2M=256).
// ws layout: [kv: 4*16*256*64 f32 = 4MB][attn: 16384*1024 f32 = 67MB] = 71.3MB.

#define DM     1024
#define NHEAD  16
#define MKP    128
#define SEQL   4096
#define NBATCH 4
#define KT     32

#define P_SCALE 0.125f                  // 1/sqrt(64)
#define F_SCALE 0.08838834764831845f    // 1/sqrt(128)

// XOR-swizzled float4-chunk offset inside a [rows][nch*4] f32 LDS tile.
// Breaks the 2-bank aliasing of stride-4-row access patterns; store & load
// must both use this. nch = f4 chunks per row (power of 2).
static __device__ __forceinline__ int swz(int r, int c4, int nch) {
  return r * (nch * 4) + ((c4 ^ (r >> 2)) & (nch - 1)) * 4;
}
static __device__ __forceinline__ float bf2f(unsigned int s) {
  return __uint_as_float(s << 16);
}
static __device__ __forceinline__ unsigned int f2bf(float f) {
  unsigned int u = __float_as_uint(f);
  u += 0x7fffu + ((u >> 16) & 1u);   // RNE
  return u >> 16;
}

// ---------------------------------------------------------------------------
// Kernel 1: per (b, h, L-chunk of 512): k/v projection -> fourier -> kv outer
// product accumulated in regs, atomicAdd flush. kv[b][h][m(256)][d(64)].
// ---------------------------------------------------------------------------
__global__ __launch_bounds__(256, 2)
void kv_accum_kernel(const float* __restrict__ x, const float* __restrict__ Wk,
                     const float* __restrict__ bk, const float* __restrict__ Wv,
                     const float* __restrict__ bv, const float* __restrict__ proj,
                     float* __restrict__ kv) {
  __shared__ float smem[14336];          // 57.3 KB
  float* xs  = smem;                     // [64][32] staging (swz, nch=8)
  float* wks = smem + 2048;
  float* wvs = smem + 4096;
  float* kt  = smem;                     // [64][64] k-tile (swz, nch=16), overlays staging
  unsigned short* vt = (unsigned short*)(smem + 4096); // [64][64] bf16 v-tile
  float* kp  = smem + 6144;              // [64][128] cos|sin of one m-half (swz, nch=32)

  const int tid = threadIdx.x;
  const int bid = blockIdx.x;
  const int chunk = bid & 7;
  const int h = (bid >> 3) & 15;
  const int b = bid >> 7;
  const int rowbase = b * SEQL + chunk * 512;

  const int tx  = tid & 15;
  const int ty  = tid >> 4;
  const int tx4 = tx * 4;
  const int ty4 = ty * 4;
  const int lr  = tid >> 3;        // staging: row 0..31
  const int lc4 = tid & 7;         // staging: f4 chunk 0..7

  float bkreg[4], bvreg[4];
#pragma unroll
  for (int j = 0; j < 4; ++j) {
    bkreg[j] = bk[h * 64 + tx4 + j];
    bvreg[j] = bv[h * 64 + tx4 + j];
  }

  // persistent kv accumulator: half hh, lm = (tid>>4)*8 + q, d = (tid&15)*4 + dd
  float acc_kv[2][8][4];
#pragma unroll
  for (int a = 0; a < 2; ++a)
#pragma unroll
    for (int q = 0; q < 8; ++q)
#pragma unroll
      for (int d = 0; d < 4; ++d) acc_kv[a][q][d] = 0.f;

  for (int st = 0; st < 8; ++st) {
    const int row0 = rowbase + st * 64;
    float acc_k[4][4], acc_v[4][4];
#pragma unroll
    for (int i = 0; i < 4; ++i)
#pragma unroll
      for (int j = 0; j < 4; ++j) { acc_k[i][j] = 0.f; acc_v[i][j] = 0.f; }

    for (int k0 = 0; k0 < DM; k0 += KT) {
#pragma unroll
      for (int i = 0; i < 2; ++i) {
        const int r = lr + i * 32;
        *(float4*)(xs  + swz(r, lc4, 8)) = *(const float4*)(x  + (size_t)(row0 + r) * DM + k0 + lc4 * 4);
        *(float4*)(wks + swz(r, lc4, 8)) = *(const float4*)(Wk + (size_t)(h * 64 + r) * DM + k0 + lc4 * 4);
        *(float4*)(wvs + swz(r, lc4, 8)) = *(const float4*)(Wv + (size_t)(h * 64 + r) * DM + k0 + lc4 * 4);
      }
      __syncthreads();
#pragma unroll 2
      for (int kk = 0; kk < KT; kk += 4) {
        const int kc = kk >> 2;
        float a[4][4], bkr[4][4], bvr[4][4];
#pragma unroll
        for (int i = 0; i < 4; ++i) {
          float4 t = *(const float4*)(xs + swz(ty4 + i, kc, 8));
          a[i][0] = t.x; a[i][1] = t.y; a[i][2] = t.z; a[i][3] = t.w;
        }
#pragma unroll
        for (int j = 0; j < 4; ++j) {
          float4 t = *(const float4*)(wks + swz(tx4 + j, kc, 8));
          bkr[j][0] = t.x; bkr[j][1] = t.y; bkr[j][2] = t.z; bkr[j][3] = t.w;
          float4 u = *(const float4*)(wvs + swz(tx4 + j, kc, 8));
          bvr[j][0] = u.x; bvr[j][1] = u.y; bvr[j][2] = u.z; bvr[j][3] = u.w;
        }
#pragma unroll
        for (int i = 0; i < 4; ++i)
#pragma unroll
          for (int j = 0; j < 4; ++j)
#pragma unroll
            for (int d = 0; d < 4; ++d) {
              acc_k[i][j] += a[i][d] * bkr[j][d];
              acc_v[i][j] += a[i][d] * bvr[j][d];
            }
      }
      __syncthreads();
    }

    // epilogue: bias; k-tile -> LDS f32, v-tile -> LDS bf16 (overlays staging)
#pragma unroll
    for (int i = 0; i < 4; ++i) {
      float4 kq;
      kq.x = acc_k[i][0] + bkreg[0];
      kq.y = acc_k[i][1] + bkreg[1];
      kq.z = acc_k[i][2] + bkreg[2];
      kq.w = acc_k[i][3] + bkreg[3];
      *(float4*)(kt + swz(ty4 + i, tx, 16)) = kq;
      unsigned int lo = f2bf(acc_v[i][0] + bvreg[0]) | (f2bf(acc_v[i][1] + bvreg[1]) << 16);
      unsigned int hi = f2bf(acc_v[i][2] + bvreg[2]) | (f2bf(acc_v[i][3] + bvreg[3]) << 16);
      *(uint2*)(vt + (ty4 + i) * 64 + tx4) = make_uint2(lo, hi);
    }
    __syncthreads();

#pragma unroll
    for (int hh = 0; hh < 2; ++hh) {
      // p[r][hh*64 + 4tx+j] = (k_row . proj_col)/8 over d=0..63
      float pa[4][4];
#pragma unroll
      for (int i = 0; i < 4; ++i)
#pragma unroll
        for (int j = 0; j < 4; ++j) pa[i][j] = 0.f;
#pragma unroll 4
      for (int dg = 0; dg < 16; ++dg) {
        float a4[4][4];
#pragma unroll
        for (int i = 0; i < 4; ++i) {
          float4 t = *(const float4*)(kt + swz(ty4 + i, dg, 16));
          a4[i][0] = t.x; a4[i][1] = t.y; a4[i][2] = t.z; a4[i][3] = t.w;
        }
#pragma unroll
        for (int dd = 0; dd < 4; ++dd) {
          float4 pm = *(const float4*)(proj + (size_t)(dg * 4 + dd) * MKP + hh * 64 + tx4);
          float pmr[4] = {pm.x, pm.y, pm.z, pm.w};
#pragma unroll
          for (int i = 0; i < 4; ++i)
#pragma unroll
            for (int j = 0; j < 4; ++j) pa[i][j] += a4[i][dd] * pmr[j];
        }
      }
      // cos -> kp cols 0..63 (chunk tx), sin -> cols 64..127 (chunk 16+tx)
#pragma unroll
      for (int i = 0; i < 4; ++i) {
        float c[4], s[4];
#pragma unroll
        for (int j = 0; j < 4; ++j) {
          float p = pa[i][j] * P_SCALE;
          float sv, cv;
          __sincosf(p, &sv, &cv);
          c[j] = cv * F_SCALE;
          s[j] = sv * F_SCALE;
        }
        *(float4*)(kp + swz(ty4 + i, tx, 32))      = make_float4(c[0], c[1], c[2], c[3]);
        *(float4*)(kp + swz(ty4 + i, 16 + tx, 32)) = make_float4(s[0], s[1], s[2], s[3]);
      }
      __syncthreads();
      // kv accumulation: lm = ty*8 + q (chunks 2ty, 2ty+1), d = tx4 + dd
#pragma unroll 4
      for (int r = 0; r < 64; ++r) {
        float4 k0v = *(const float4*)(kp + swz(r, 2 * ty, 32));
        float4 k1v = *(const float4*)(kp + swz(r, 2 * ty + 1, 32));
        float kpr[8] = {k0v.x, k0v.y, k0v.z, k0v.w, k1v.x, k1v.y, k1v.z, k1v.w};
        uint2 vu = *(const uint2*)(vt + r * 64 + tx4);
        float vr[4] = {bf2f(vu.x & 0xffffu), bf2f(vu.x >> 16),
                       bf2f(vu.y & 0xffffu), bf2f(vu.y >> 16)};
#pragma unroll
        for (int q = 0; q < 8; ++q)
#pragma unroll
          for (int d = 0; d < 4; ++d) acc_kv[hh][q][d] += kpr[q] * vr[d];
      }
      __syncthreads();
    }
  }

  // flush: lm<64 -> cos slot hh*64+lm ; lm>=64 -> sin slot 128+hh*64+(lm-64)
  float* kvb = kv + (size_t)(b * NHEAD + h) * 256 * 64;
#pragma unroll
  for (int hh = 0; hh < 2; ++hh)
#pragma unroll
    for (int q = 0; q < 8; ++q) {
      const int lm = ty * 8 + q;
      const int gm = (lm < 64) ? (hh * 64 + lm) : (128 + hh * 64 + (lm - 64));
#pragma unroll
      for (int d = 0; d < 4; ++d)
        atomicAdd(kvb + (size_t)gm * 64 + tx4 + d, acc_kv[hh][q][d]);
    }
}

// ---------------------------------------------------------------------------
// Kernel 2: per (64-row tile, h): q projection -> fourier -> q' @ kv[b,h]
// -> attn[row][h*64+d]
// ---------------------------------------------------------------------------
__global__ __launch_bounds__(256, 2)
void q_attn_kernel(const float* __restrict__ x, const float* __restrict__ Wq,
                   const float* __restrict__ bq, const float* __restrict__ proj,
                   const float* __restrict__ kv, float* __restrict__ attn) {
  __shared__ float smem[12288];          // 48 KB
  float* xs  = smem;                     // [64][32]
  float* wqs = smem + 2048;
  float* qt  = smem;                     // [64][64] overlays staging
  float* qp  = smem + 4096;              // [64][128]

  const int tid = threadIdx.x;
  const int bid = blockIdx.x;
  const int tile = bid & 255;
  const int h = bid >> 8;
  const int row0 = tile * 64;
  const int b = tile >> 6;

  const int tx  = tid & 15;
  const int ty  = tid >> 4;
  const int tx4 = tx * 4;
  const int ty4 = ty * 4;
  const int lr  = tid >> 3;
  const int lc4 = tid & 7;

  float bqreg[4];
#pragma unroll
  for (int j = 0; j < 4; ++j) bqreg[j] = bq[h * 64 + tx4 + j];

  float acc_q[4][4];
#pragma unroll
  for (int i = 0; i < 4; ++i)
#pragma unroll
    for (int j = 0; j < 4; ++j) acc_q[i][j] = 0.f;

  for (int k0 = 0; k0 < DM; k0 += KT) {
#pragma unroll
    for (int i = 0; i < 2; ++i) {
      const int r = lr + i * 32;
      *(float4*)(xs  + swz(r, lc4, 8)) = *(const float4*)(x  + (size_t)(row0 + r) * DM + k0 + lc4 * 4);
      *(float4*)(wqs + swz(r, lc4, 8)) = *(const float4*)(Wq + (size_t)(h * 64 + r) * DM + k0 + lc4 * 4);
    }
    __syncthreads();
#pragma unroll 2
    for (int kk = 0; kk < KT; kk += 4) {
      const int kc = kk >> 2;
      float a[4][4], bqr[4][4];
#pragma unroll
      for (int i = 0; i < 4; ++i) {
        float4 t = *(const float4*)(xs + swz(ty4 + i, kc, 8));
        a[i][0] = t.x; a[i][1] = t.y; a[i][2] = t.z; a[i][3] = t.w;
      }
#pragma unroll
      for (int j = 0; j < 4; ++j) {
        float4 t = *(const float4*)(wqs + swz(tx4 + j, kc, 8));
        bqr[j][0] = t.x; bqr[j][1] = t.y; bqr[j][2] = t.z; bqr[j][3] = t.w;
      }
#pragma unroll
      for (int i = 0; i < 4; ++i)
#pragma unroll
        for (int j = 0; j < 4; ++j)
#pragma unroll
          for (int d = 0; d < 4; ++d) acc_q[i][j] += a[i][d] * bqr[j][d];
    }
    __syncthreads();
  }

#pragma unroll
  for (int i = 0; i < 4; ++i) {
    float4 qq;
    qq.x = acc_q[i][0] + bqreg[0];
    qq.y = acc_q[i][1] + bqreg[1];
    qq.z = acc_q[i][2] + bqreg[2];
    qq.w = acc_q[i][3] + bqreg[3];
    *(float4*)(qt + swz(ty4 + i, tx, 16)) = qq;
  }
  __syncthreads();

  const float* kvb = kv + (size_t)(b * NHEAD + h) * 256 * 64;
  float acc_a[4][4];
#pragma unroll
  for (int i = 0; i < 4; ++i)
#pragma unroll
    for (int j = 0; j < 4; ++j) acc_a[i][j] = 0.f;

#pragma unroll
  for (int hh = 0; hh < 2; ++hh) {
    float pa[4][4];
#pragma unroll
    for (int i = 0; i < 4; ++i)
#pragma unroll
      for (int j = 0; j < 4; ++j) pa[i][j] = 0.f;
#pragma unroll 4
    for (int dg = 0; dg < 16; ++dg) {
      float a4[4][4];
#pragma unroll
      for (int i = 0; i < 4; ++i) {
        float4 t = *(const float4*)(qt + swz(ty4 + i, dg, 16));
        a4[i][0] = t.x; a4[i][1] = t.y; a4[i][2] = t.z; a4[i][3] = t.w;
      }
#pragma unroll
      for (int dd = 0; dd < 4; ++dd) {
        float4 pm = *(const float4*)(proj + (size_t)(dg * 4 + dd) * MKP + hh * 64 + tx4);
        float pmr[4] = {pm.x, pm.y, pm.z, pm.w};
#pragma unroll
        for (int i = 0; i < 4; ++i)
#pragma unroll
          for (int j = 0; j < 4; ++j) pa[i][j] += a4[i][dd] * pmr[j];
      }
    }
#pragma unroll
    for (int i = 0; i < 4; ++i) {
      float c[4], s[4];
#pragma unroll
      for (int j = 0; j < 4; ++j) {
        float p = pa[i][j] * P_SCALE;
        float sv, cv;
        __sincosf(p, &sv, &cv);
        c[j] = cv * F_SCALE;
        s[j] = sv * F_SCALE;
      }
      *(float4*)(qp + swz(ty4 + i, tx, 32))      = make_float4(c[0], c[1], c[2], c[3]);
      *(float4*)(qp + swz(ty4 + i, 16 + tx, 32)) = make_float4(s[0], s[1], s[2], s[3]);
    }
    __syncthreads();
    // attn += q'[rows][this half's 128 cols] @ kv[those gm][d]
#pragma unroll
    for (int seg = 0; seg < 2; ++seg) {
      const int gmb = (seg == 0) ? hh * 64 : 128 + hh * 64;
#pragma unroll 2
      for (int mg = 0; mg < 16; ++mg) {
        float a4[4][4];
#pragma unroll
        for (int i = 0; i < 4; ++i) {
          float4 t = *(const float4*)(qp + swz(ty4 + i, seg * 16 + mg, 32));
          a4[i][0] = t.x; a4[i][1] = t.y; a4[i][2] = t.z; a4[i][3] = t.w;
        }
        float kvr[4][4];
#pragma unroll
        for (int mi = 0; mi < 4; ++mi) {
          float4 t = *(const float4*)(kvb + (size_t)(gmb + mg * 4 + mi) * 64 + tx4);
          kvr[mi][0] = t.x; kvr[mi][1] = t.y; kvr[mi][2] = t.z; kvr[mi][3] = t.w;
        }
#pragma unroll
        for (int i = 0; i < 4; ++i)
#pragma unroll
          for (int j = 0; j < 4; ++j)
#pragma unroll
            for (int mi = 0; mi < 4; ++mi) acc_a[i][j] += a4[i][mi] * kvr[mi][j];
      }
    }
    __syncthreads();
  }

#pragma unroll
  for (int i = 0; i < 4; ++i) {
    float4 o = make_float4(acc_a[i][0], acc_a[i][1], acc_a[i][2], acc_a[i][3]);
    *(float4*)(attn + (size_t)(row0 + ty4 + i) * DM + h * 64 + tx4) = o;
  }
}

// ---------------------------------------------------------------------------
// Kernel 3: out = attn @ Wo^T + bo   (16384x1024 @ 1024x1024^T)
// ---------------------------------------------------------------------------
__global__ __launch_bounds__(256, 2)
void out_proj_kernel(const float* __restrict__ attn, const float* __restrict__ Wo,
                     const float* __restrict__ bo, float* __restrict__ out) {
  __shared__ float smem[4096];           // 16 KB
  float* xs  = smem;
  float* wos = smem + 2048;

  const int tid = threadIdx.x;
  const int bid = blockIdx.x;
  const int tile_m = bid & 255;
  const int tn = bid >> 8;
  const int row0 = tile_m * 64;
  const int col0 = tn * 64;

  const int tx4 = (tid & 15) * 4;
  const int ty4 = (tid >> 4) * 4;
  const int lr  = tid >> 3;
  const int lc4 = tid & 7;

  float boreg[4];
#pragma unroll
  for (int j = 0; j < 4; ++j) boreg[j] = bo[col0 + tx4 + j];

  float acc[4][4];
#pragma unroll
  for (int i = 0; i < 4; ++i)
#pragma unroll
    for (int j = 0; j < 4; ++j) acc[i][j] = 0.f;

  for (int k0 = 0; k0 < DM; k0 += KT) {
#pragma unroll
    for (int i = 0; i < 2; ++i) {
      const int r = lr + i * 32;
      *(float4*)(xs  + swz(r, lc4, 8)) = *(const float4*)(attn + (size_t)(row0 + r) * DM + k0 + lc4 * 4);
      *(float4*)(wos + swz(r, lc4, 8)) = *(const float4*)(Wo   + (size_t)(col0 + r) * DM + k0 + lc4 * 4);
    }
    __syncthreads();
#pragma unroll 2
    for (int kk = 0; kk < KT; kk += 4) {
      const int kc = kk >> 2;
      float a[4][4], br[4][4];
#pragma unroll
      for (int i = 0; i < 4; ++i) {
        float4 t = *(const float4*)(xs + swz(ty4 + i, kc, 8));
        a[i][0] = t.x; a[i][1] = t.y; a[i][2] = t.z; a[i][3] = t.w;
      }
#pragma unroll
      for (int j = 0; j < 4; ++j) {
        float4 t = *(const float4*)(wos + swz(tx4 + j, kc, 8));
        br[j][0] = t.x; br[j][1] = t.y; br[j][2] = t.z; br[j][3] = t.w;
      }
#pragma unroll
      for (int i = 0; i < 4; ++i)
#pragma unroll
        for (int j = 0; j < 4; ++j)
#pragma unroll
          for (int d = 0; d < 4; ++d) acc[i][j] += a[i][d] * br[j][d];
    }
    __syncthreads();
  }

#pragma unroll
  for (int i = 0; i < 4; ++i) {
    float4 o;
    o.x = acc[i][0] + boreg[0];
    o.y = acc[i][1] + boreg[1];
    o.z = acc[i][2] + boreg[2];
    o.w = acc[i][3] + boreg[3];
    *(float4*)(out + (size_t)(row0 + ty4 + i) * DM + col0 + tx4) = o;
  }
}

extern "C" void kernel_launch(void* const* d_in, const int* in_sizes, int n_in,
                              void* d_out, int out_size, void* d_ws, size_t ws_size,
                              hipStream_t stream) {
  const float* x    = (const float*)d_in[0];
  const float* proj = (const float*)d_in[1];
  const float* Wq   = (const float*)d_in[2];
  const float* bq   = (const float*)d_in[3];
  const float* Wk   = (const float*)d_in[4];
  const float* bk   = (const float*)d_in[5];
  const float* Wv   = (const float*)d_in[6];
  const float* bv   = (const float*)d_in[7];
  const float* Wo   = (const float*)d_in[8];
  const float* bo   = (const float*)d_in[9];
  float* out = (float*)d_out;

  const size_t kv_bytes = (size_t)NBATCH * NHEAD * 256 * 64 * sizeof(float); // 4 MB
  float* kv   = (float*)d_ws;
  float* attn = (float*)((char*)d_ws + kv_bytes);                            // 67 MB

  hipMemsetAsync(d_ws, 0, kv_bytes, stream);
  kv_accum_kernel<<<dim3(512), dim3(256), 0, stream>>>(x, Wk, bk, Wv, bv, proj, kv);
  q_attn_kernel<<<dim3(4096), dim3(256), 0, stream>>>(x, Wq, bq, proj, kv, attn);
  out_proj_kernel<<<dim3(4096), dim3(256), 0, stream>>>(attn, Wo, bo, out);
}

// Round 2
// 527.600 us; speedup vs baseline: 5.3058x; 5.3058x over previous
//
#include <hip/hip_runtime.h>
#include <cstddef>
#include <cstdint>

// LinearAttention — bf16 MFMA implementation.
// B=4 L=4096 D=1024 H=16 d=64 M=128 (2M=256).
// Pipeline: convert weights -> K1 fused QKV GEMM (epilogue: q,k natural bf16;
// v transposed) -> K2 fourier(k)+kv outer (atomicAdd fp32) -> K2.5 kv->kvT bf16
// -> K3 fourier(q)+attn -> K4 out GEMM.
//
// ws layout (bytes):
//   qb     @ 0          33.55MB  bf16 [16384][1024]
//   kb     @ 33554432   33.55MB  bf16 [16384][1024]   (reused as attnb after K2)
//   vT     @ 67108864   33.55MB  bf16 [64 bh*d rows? -> [(b*16+h)*64+d][4096]]
//                                 (reused as kvT after K2.5: [(bh*64+d)][256])
//   kv     @ 100663296   4.19MB  f32  [64 bh][256 m][64 d]
//   Wqkvb  @ 104857600   6.29MB  bf16 [3072][1024]
//   Wob    @ 111149056   2.10MB  bf16 [1024][1024]
//   projT  @ 113246208   16KB    bf16 [128 m][64 d]
// total ~108MB.

typedef __attribute__((ext_vector_type(8))) short s8v;   // 8 x bf16 (4 VGPR)
typedef __attribute__((ext_vector_type(4))) short s4v;   // 4 x bf16 (8B)
typedef __attribute__((ext_vector_type(4))) float f32x4; // MFMA acc

#define MFMA_BF16(a, b, c) __builtin_amdgcn_mfma_f32_16x16x32_bf16((a), (b), (c), 0, 0, 0)

#define P_SCALE 0.125f                 // 1/sqrt(64)
#define F_SCALE 0.08838834764831845f   // 1/sqrt(128)

static __device__ __forceinline__ unsigned short f2bf(float f) {
  unsigned int u = __float_as_uint(f);
  u += 0x7fffu + ((u >> 16) & 1u);  // RNE
  return (unsigned short)(u >> 16);
}

// ---------------------------------------------------------------------------
// K0a: fp32 -> bf16 elementwise convert (weights)
// ---------------------------------------------------------------------------
__global__ void conv_bf16_kernel(const float* __restrict__ src, short* __restrict__ dst, int n) {
  int i4 = (blockIdx.x * 256 + threadIdx.x) * 4;
  if (i4 < n) {
    float4 f = *(const float4*)(src + i4);
    s4v v;
    v[0] = (short)f2bf(f.x); v[1] = (short)f2bf(f.y);
    v[2] = (short)f2bf(f.z); v[3] = (short)f2bf(f.w);
    *(s4v*)(dst + i4) = v;
  }
}

// K0b: proj [64][128] f32 -> projT [128][64] bf16
__global__ void projT_kernel(const float* __restrict__ proj, short* __restrict__ projT) {
  int t = threadIdx.x;
#pragma unroll
  for (int i = 0; i < 32; ++i) {
    int idx = t + i * 256;
    int d = idx >> 7, m = idx & 127;
    projT[m * 64 + d] = (short)f2bf(proj[idx]);
  }
}

// ---------------------------------------------------------------------------
// K1: qkv = x @ Wqkv^T + bias. 128x128 tile, BK=64, bf16 MFMA.
// grid (128 row-tiles, 24 col-tiles). col-tiles 0-7: q, 8-15: k, 16-23: v.
// q/k: write bf16 natural. v: write transposed vT[(b*16+h)*64+d][l].
// ---------------------------------------------------------------------------
__global__ void qkv_gemm_kernel(const float* __restrict__ x,
                                const short* __restrict__ Wqkv,
                                const float* __restrict__ bq_, const float* __restrict__ bk_,
                                const float* __restrict__ bv_,
                                short* __restrict__ qb, short* __restrict__ kb,
                                short* __restrict__ vT) {
  __shared__ short smem[18432];   // A[128][72] + B[128][72] = 36.9KB; epilogue image overlays
  short* Al = smem;
  short* Bl = smem + 9216;

  const int t = threadIdx.x;
  const int bm = blockIdx.x, bn = blockIdx.y;
  const int row0 = bm * 128, n0 = bn * 128;
  const int lane = t & 63, w = t >> 6;
  const int wm = w & 1, wn = w >> 1;
  const int l15 = lane & 15, lq = lane >> 4;

  f32x4 acc[4][4];
#pragma unroll
  for (int i = 0; i < 4; ++i)
#pragma unroll
    for (int j = 0; j < 4; ++j) acc[i][j] = (f32x4){0.f, 0.f, 0.f, 0.f};

  for (int k0 = 0; k0 < 1024; k0 += 64) {
#pragma unroll
    for (int i = 0; i < 4; ++i) {
      int c = t + i * 256;              // 1024 chunks of 8 elems
      int r = c >> 3, cc = c & 7;
      const float* gp = x + (size_t)(row0 + r) * 1024 + k0 + cc * 8;
      float4 f0 = *(const float4*)gp;
      float4 f1 = *(const float4*)(gp + 4);
      s8v v;
      v[0] = (short)f2bf(f0.x); v[1] = (short)f2bf(f0.y);
      v[2] = (short)f2bf(f0.z); v[3] = (short)f2bf(f0.w);
      v[4] = (short)f2bf(f1.x); v[5] = (short)f2bf(f1.y);
      v[6] = (short)f2bf(f1.z); v[7] = (short)f2bf(f1.w);
      *(s8v*)&Al[r * 72 + cc * 8] = v;
      *(s8v*)&Bl[r * 72 + cc * 8] =
          *(const s8v*)(Wqkv + (size_t)(n0 + r) * 1024 + k0 + cc * 8);
    }
    __syncthreads();
#pragma unroll
    for (int ks = 0; ks < 2; ++ks) {
      s8v af[4], bfr[4];
#pragma unroll
      for (int i = 0; i < 4; ++i)
        af[i] = *(s8v*)&Al[(wm * 64 + i * 16 + l15) * 72 + ks * 32 + lq * 8];
#pragma unroll
      for (int j = 0; j < 4; ++j)
        bfr[j] = *(s8v*)&Bl[(wn * 64 + j * 16 + l15) * 72 + ks * 32 + lq * 8];
#pragma unroll
      for (int i = 0; i < 4; ++i)
#pragma unroll
        for (int j = 0; j < 4; ++j)
          acc[i][j] = MFMA_BF16(af[i], bfr[j], acc[i][j]);
    }
    __syncthreads();
  }

  const int region = bn >> 3;  // 0 q, 1 k, 2 v
  if (region < 2) {
    const float* bias = (region == 0) ? bq_ : bk_;
    short* IM = smem;  // [128][136] natural image
#pragma unroll
    for (int j = 0; j < 4; ++j) {
      int cl = wn * 64 + j * 16 + l15;
      float bsv = bias[(n0 & 1023) + cl];
#pragma unroll
      for (int i = 0; i < 4; ++i)
#pragma unroll
        for (int r = 0; r < 4; ++r)
          IM[(wm * 64 + i * 16 + lq * 4 + r) * 136 + cl] = (short)f2bf(acc[i][j][r] + bsv);
    }
    __syncthreads();
    short* dst = (region == 0) ? qb : kb;
#pragma unroll
    for (int i = 0; i < 8; ++i) {
      int c = t + i * 256;
      int r = c >> 4, cc = c & 15;
      *(s8v*)&dst[(size_t)(row0 + r) * 1024 + (n0 & 1023) + cc * 8] =
          *(s8v*)&IM[r * 136 + cc * 8];
    }
  } else {
    short* IM = smem;  // [128 col][136] transposed image
#pragma unroll
    for (int j = 0; j < 4; ++j) {
      int cl = wn * 64 + j * 16 + l15;
      float bsv = bv_[(n0 - 2048) + cl];
#pragma unroll
      for (int i = 0; i < 4; ++i) {
        s4v pk;
#pragma unroll
        for (int r = 0; r < 4; ++r) pk[r] = (short)f2bf(acc[i][j][r] + bsv);
        *(s4v*)&IM[cl * 136 + wm * 64 + i * 16 + lq * 4] = pk;
      }
    }
    __syncthreads();
    const int b = row0 >> 12;
    const int l0 = (bm & 31) * 128;
#pragma unroll
    for (int i = 0; i < 8; ++i) {
      int c = t + i * 256;
      int ci = c >> 4, cc = c & 15;
      int cv = (bn - 16) * 128 + ci;      // 0..1023
      int grow = (b * 16 + (cv >> 6)) * 64 + (cv & 63);
      *(s8v*)&vT[(size_t)grow * 4096 + l0 + cc * 8] = *(s8v*)&IM[ci * 136 + cc * 8];
    }
  }
}

// ---------------------------------------------------------------------------
// K2: per (b,h,512-row chunk): fourier(k) -> k' ; kv += k'^T @ v  (MFMA),
// atomicAdd f32 flush. grid 512.
// ---------------------------------------------------------------------------
__global__ void kv_accum_kernel(const short* __restrict__ kb, const short* __restrict__ vT,
                                const short* __restrict__ projT, float* __restrict__ kv) {
  __shared__ short smem[27648];  // kt[64][72] + vt[64][72] + kpT[256][72] = 55.3KB
  short* kt = smem;
  short* vt = smem + 4608;
  short* kpT = smem + 9216;

  const int t = threadIdx.x;
  const int bid = blockIdx.x;
  const int chunk = bid & 7, h = (bid >> 3) & 15, b = bid >> 7;
  const int lane = t & 63, w = t >> 6;
  const int l15 = lane & 15, lq = lane >> 4;

  // preload projT B-fragments: pf[nt][ks], nt: m'-tile (0..7), ks: k-step
  s8v pf[8][2];
#pragma unroll
  for (int nt = 0; nt < 8; ++nt)
#pragma unroll
    for (int ks = 0; ks < 2; ++ks)
      pf[nt][ks] = *(const s8v*)(projT + (size_t)(nt * 16 + l15) * 64 + ks * 32 + lq * 8);

  f32x4 kvacc[4][4];
#pragma unroll
  for (int i = 0; i < 4; ++i)
#pragma unroll
    for (int j = 0; j < 4; ++j) kvacc[i][j] = (f32x4){0.f, 0.f, 0.f, 0.f};

  for (int s = 0; s < 8; ++s) {
    const int l0s = chunk * 512 + s * 64;     // local L-offset in batch b
#pragma unroll
    for (int i = 0; i < 2; ++i) {
      int c = t + i * 256;                    // 512 chunks
      int r = c >> 3, cc = c & 7;
      *(s8v*)&kt[r * 72 + cc * 8] =
          *(const s8v*)(kb + (size_t)(b * 4096 + l0s + r) * 1024 + h * 64 + cc * 8);
      *(s8v*)&vt[r * 72 + cc * 8] =
          *(const s8v*)(vT + (size_t)((b * 16 + h) * 64 + r) * 4096 + l0s + cc * 8);
    }
    __syncthreads();

    // fourier: p[row][m'] = k_tile @ proj ; wave w handles rows w*16..+15
    f32x4 pacc[8];
#pragma unroll
    for (int nt = 0; nt < 8; ++nt) pacc[nt] = (f32x4){0.f, 0.f, 0.f, 0.f};
#pragma unroll
    for (int ks = 0; ks < 2; ++ks) {
      s8v af = *(s8v*)&kt[(w * 16 + l15) * 72 + ks * 32 + lq * 8];
#pragma unroll
      for (int nt = 0; nt < 8; ++nt) pacc[nt] = MFMA_BF16(af, pf[nt][ks], pacc[nt]);
    }
    // sincos -> k'T[m][row] (cos: m'=0..127, sin: +128), packed 4-row b64 writes
#pragma unroll
    for (int nt = 0; nt < 8; ++nt) {
      s4v cp, sp;
#pragma unroll
      for (int r = 0; r < 4; ++r) {
        float p = pacc[nt][r] * P_SCALE;
        float sv, cv;
        __sincosf(p, &sv, &cv);
        cp[r] = (short)f2bf(cv * F_SCALE);
        sp[r] = (short)f2bf(sv * F_SCALE);
      }
      int m = nt * 16 + l15;
      int rbase = w * 16 + lq * 4;
      *(s4v*)&kpT[m * 72 + rbase] = cp;
      *(s4v*)&kpT[(m + 128) * 72 + rbase] = sp;
    }
    __syncthreads();

    // kv MFMA: wave w: m-range w*64..+63, full d (64)
#pragma unroll
    for (int ks = 0; ks < 2; ++ks) {
      s8v af[4], bf4[4];
#pragma unroll
      for (int i = 0; i < 4; ++i)
        af[i] = *(s8v*)&kpT[(w * 64 + i * 16 + l15) * 72 + ks * 32 + lq * 8];
#pragma unroll
      for (int j = 0; j < 4; ++j)
        bf4[j] = *(s8v*)&vt[(j * 16 + l15) * 72 + ks * 32 + lq * 8];
#pragma unroll
      for (int i = 0; i < 4; ++i)
#pragma unroll
        for (int j = 0; j < 4; ++j)
          kvacc[i][j] = MFMA_BF16(af[i], bf4[j], kvacc[i][j]);
    }
    __syncthreads();
  }

  float* kvb = kv + ((size_t)(b * 16 + h) << 14);
#pragma unroll
  for (int i = 0; i < 4; ++i)
#pragma unroll
    for (int j = 0; j < 4; ++j)
#pragma unroll
      for (int r = 0; r < 4; ++r) {
        int m = w * 64 + i * 16 + lq * 4 + r;
        int d = j * 16 + l15;
        atomicAdd(kvb + (size_t)m * 64 + d, kvacc[i][j][r]);
      }
}

// ---------------------------------------------------------------------------
// K2.5: kv f32 [bh][256][64] -> kvT bf16 [bh*64+d][256]. grid 64.
// ---------------------------------------------------------------------------
__global__ void kvT_kernel(const float* __restrict__ kv, short* __restrict__ kvT) {
  __shared__ short im[16896];  // [64][264]
  const int t = threadIdx.x;
  const int bh = blockIdx.x;
  const float* src = kv + ((size_t)bh << 14);
#pragma unroll
  for (int i = 0; i < 64; ++i) {
    int idx = t + i * 256;
    int m = idx >> 6, d = idx & 63;
    im[d * 264 + m] = (short)f2bf(src[idx]);
  }
  __syncthreads();
#pragma unroll
  for (int i = 0; i < 8; ++i) {
    int c = t + i * 256;
    int d = c >> 5, cc = c & 31;
    *(s8v*)&kvT[(size_t)(bh * 64 + d) * 256 + cc * 8] = *(s8v*)&im[d * 264 + cc * 8];
  }
}

// ---------------------------------------------------------------------------
// K3: fourier(q) + attn = q' @ kv, per (64-row tile, head). grid (256,16).
// Processes m-halves (cos then sin) to bound LDS.
// ---------------------------------------------------------------------------
__global__ void attn_kernel(const short* __restrict__ qb, const short* __restrict__ projT,
                            const short* __restrict__ kvT, short* __restrict__ attnb) {
  __shared__ short smem[22016];  // qt[64][72] + qA[64][136] + kvt[64][136] = 44KB
  short* qt = smem;
  short* qA = smem + 4608;
  short* kvt = smem + 13312;

  const int t = threadIdx.x;
  const int rt = blockIdx.x, h = blockIdx.y;
  const int row0 = rt * 64;
  const int b = row0 >> 12;
  const int lane = t & 63, w = t >> 6;
  const int l15 = lane & 15, lq = lane >> 4;

  s8v pf[8][2];
#pragma unroll
  for (int nt = 0; nt < 8; ++nt)
#pragma unroll
    for (int ks = 0; ks < 2; ++ks)
      pf[nt][ks] = *(const s8v*)(projT + (size_t)(nt * 16 + l15) * 64 + ks * 32 + lq * 8);

#pragma unroll
  for (int i = 0; i < 2; ++i) {
    int c = t + i * 256;
    int r = c >> 3, cc = c & 7;
    *(s8v*)&qt[r * 72 + cc * 8] =
        *(const s8v*)(qb + (size_t)(row0 + r) * 1024 + h * 64 + cc * 8);
  }
  __syncthreads();

  // p = q_tile @ proj, wave w: rows w*16..+15
  f32x4 pacc[8];
#pragma unroll
  for (int nt = 0; nt < 8; ++nt) pacc[nt] = (f32x4){0.f, 0.f, 0.f, 0.f};
#pragma unroll
  for (int ks = 0; ks < 2; ++ks) {
    s8v af = *(s8v*)&qt[(w * 16 + l15) * 72 + ks * 32 + lq * 8];
#pragma unroll
    for (int nt = 0; nt < 8; ++nt) pacc[nt] = MFMA_BF16(af, pf[nt][ks], pacc[nt]);
  }

  f32x4 aacc[4];
#pragma unroll
  for (int j = 0; j < 4; ++j) aacc[j] = (f32x4){0.f, 0.f, 0.f, 0.f};

#pragma unroll
  for (int half = 0; half < 2; ++half) {
    // q' half -> qA [64][136] natural
#pragma unroll
    for (int nt = 0; nt < 8; ++nt)
#pragma unroll
      for (int r = 0; r < 4; ++r) {
        float p = pacc[nt][r] * P_SCALE;
        float fv = (half == 0) ? __cosf(p) : __sinf(p);
        qA[(w * 16 + lq * 4 + r) * 136 + nt * 16 + l15] = (short)f2bf(fv * F_SCALE);
      }
    // stage kvT half: [64 d][128 m']
#pragma unroll
    for (int i = 0; i < 4; ++i) {
      int c = t + i * 256;                 // 1024 chunks
      int d = c >> 4, cc = c & 15;
      *(s8v*)&kvt[d * 136 + cc * 8] =
          *(const s8v*)(kvT + (size_t)((b * 16 + h) * 64 + d) * 256 + half * 128 + cc * 8);
    }
    __syncthreads();
    // attn += q'_half [64][128] @ kv_half [128][64]; wave w: row-tile w
#pragma unroll
    for (int ks = 0; ks < 4; ++ks) {
      s8v af = *(s8v*)&qA[(w * 16 + l15) * 136 + ks * 32 + lq * 8];
#pragma unroll
      for (int j = 0; j < 4; ++j) {
        s8v bf4 = *(s8v*)&kvt[(j * 16 + l15) * 136 + ks * 32 + lq * 8];
        aacc[j] = MFMA_BF16(af, bf4, aacc[j]);
      }
    }
    __syncthreads();
  }

  // epilogue: natural bf16 write via image in qt region
#pragma unroll
  for (int j = 0; j < 4; ++j)
#pragma unroll
    for (int r = 0; r < 4; ++r)
      qt[(w * 16 + lq * 4 + r) * 72 + j * 16 + l15] = (short)f2bf(aacc[j][r]);
  __syncthreads();
#pragma unroll
  for (int i = 0; i < 2; ++i) {
    int c = t + i * 256;
    int r = c >> 3, cc = c & 7;
    *(s8v*)&attnb[(size_t)(row0 + r) * 1024 + h * 64 + cc * 8] = *(s8v*)&qt[r * 72 + cc * 8];
  }
}

// ---------------------------------------------------------------------------
// K4: out = attn @ Wo^T + bo. fp32 out. grid (128, 8).
// ---------------------------------------------------------------------------
__global__ void out_gemm_kernel(const short* __restrict__ attnb, const short* __restrict__ Wob,
                                const float* __restrict__ bo_, float* __restrict__ out) {
  __shared__ short smem[18432];
  short* Al = smem;
  short* Bl = smem + 9216;

  const int t = threadIdx.x;
  const int bm = blockIdx.x, bn = blockIdx.y;
  const int row0 = bm * 128, n0 = bn * 128;
  const int lane = t & 63, w = t >> 6;
  const int wm = w & 1, wn = w >> 1;
  const int l15 = lane & 15, lq = lane >> 4;

  f32x4 acc[4][4];
#pragma unroll
  for (int i = 0; i < 4; ++i)
#pragma unroll
    for (int j = 0; j < 4; ++j) acc[i][j] = (f32x4){0.f, 0.f, 0.f, 0.f};

  for (int k0 = 0; k0 < 1024; k0 += 64) {
#pragma unroll
    for (int i = 0; i < 4; ++i) {
      int c = t + i * 256;
      int r = c >> 3, cc = c & 7;
      *(s8v*)&Al[r * 72 + cc * 8] =
          *(const s8v*)(attnb + (size_t)(row0 + r) * 1024 + k0 + cc * 8);
      *(s8v*)&Bl[r * 72 + cc * 8] =
          *(const s8v*)(Wob + (size_t)(n0 + r) * 1024 + k0 + cc * 8);
    }
    __syncthreads();
#pragma unroll
    for (int ks = 0; ks < 2; ++ks) {
      s8v af[4], bfr[4];
#pragma unroll
      for (int i = 0; i < 4; ++i)
        af[i] = *(s8v*)&Al[(wm * 64 + i * 16 + l15) * 72 + ks * 32 + lq * 8];
#pragma unroll
      for (int j = 0; j < 4; ++j)
        bfr[j] = *(s8v*)&Bl[(wn * 64 + j * 16 + l15) * 72 + ks * 32 + lq * 8];
#pragma unroll
      for (int i = 0; i < 4; ++i)
#pragma unroll
        for (int j = 0; j < 4; ++j)
          acc[i][j] = MFMA_BF16(af[i], bfr[j], acc[i][j]);
    }
    __syncthreads();
  }

#pragma unroll
  for (int j = 0; j < 4; ++j) {
    int cl = wn * 64 + j * 16 + l15;
    float bsv = bo_[n0 + cl];
#pragma unroll
    for (int i = 0; i < 4; ++i)
#pragma unroll
      for (int r = 0; r < 4; ++r)
        out[(size_t)(row0 + wm * 64 + i * 16 + lq * 4 + r) * 1024 + n0 + cl] =
            acc[i][j][r] + bsv;
  }
}

// ---------------------------------------------------------------------------
extern "C" void kernel_launch(void* const* d_in, const int* in_sizes, int n_in,
                              void* d_out, int out_size, void* d_ws, size_t ws_size,
                              hipStream_t stream) {
  const float* x    = (const float*)d_in[0];
  const float* proj = (const float*)d_in[1];
  const float* Wq   = (const float*)d_in[2];
  const float* bq   = (const float*)d_in[3];
  const float* Wk   = (const float*)d_in[4];
  const float* bk   = (const float*)d_in[5];
  const float* Wv   = (const float*)d_in[6];
  const float* bv   = (const float*)d_in[7];
  const float* Wo   = (const float*)d_in[8];
  const float* bo   = (const float*)d_in[9];
  float* out = (float*)d_out;

  char* wsb = (char*)d_ws;
  short* qb    = (short*)(wsb + 0);
  short* kb    = (short*)(wsb + 33554432);
  short* vT    = (short*)(wsb + 67108864);
  float* kv    = (float*)(wsb + 100663296);
  short* Wqkvb = (short*)(wsb + 104857600);
  short* Wob   = (short*)(wsb + 111149056);
  short* projT = (short*)(wsb + 113246208);
  short* attnb = kb;   // kb dead after K2
  short* kvT   = vT;   // vT dead after K2

  const int WN = 1024 * 1024;  // one weight matrix
  conv_bf16_kernel<<<dim3(WN / 1024), dim3(256), 0, stream>>>(Wq, Wqkvb, WN);
  conv_bf16_kernel<<<dim3(WN / 1024), dim3(256), 0, stream>>>(Wk, Wqkvb + WN, WN);
  conv_bf16_kernel<<<dim3(WN / 1024), dim3(256), 0, stream>>>(Wv, Wqkvb + 2 * WN, WN);
  conv_bf16_kernel<<<dim3(WN / 1024), dim3(256), 0, stream>>>(Wo, Wob, WN);
  projT_kernel<<<dim3(1), dim3(256), 0, stream>>>(proj, projT);
  hipMemsetAsync(kv, 0, 4194304, stream);

  qkv_gemm_kernel<<<dim3(128, 24), dim3(256), 0, stream>>>(x, Wqkvb, bq, bk, bv, qb, kb, vT);
  kv_accum_kernel<<<dim3(512), dim3(256), 0, stream>>>(kb, vT, projT, kv);
  kvT_kernel<<<dim3(64), dim3(256), 0, stream>>>(kv, kvT);
  attn_kernel<<<dim3(256, 16), dim3(256), 0, stream>>>(qb, projT, kvT, attnb);
  out_gemm_kernel<<<dim3(128, 8), dim3(256), 0, stream>>>(attnb, Wob, bo, out);
}

// Round 3
// 433.132 us; speedup vs baseline: 6.4631x; 1.2181x over previous
//
#include <hip/hip_runtime.h>
#include <cstddef>
#include <cstdint>

// LinearAttention — bf16 MFMA, global_load_lds staging, XOR-swizzled LDS.
// B=4 L=4096 D=1024 H=16 d=64 M=128 (2M=256).
// Pipeline: convert x+weights -> K1 fused QKV GEMM (q,k natural; v transposed)
// -> K2 fourier(k)+kv outer (atomicAdd fp32) -> K2.5 kv->kvT bf16
// -> K3 fourier(q)+attn -> K4 out GEMM.
//
// ws layout (bytes):
//   qb     @ 0          33.55MB  bf16 [16384][1024]
//   kb     @ 33554432   33.55MB  bf16 [16384][1024]   (reused as attnb)
//   vT     @ 67108864   33.55MB  bf16 [(b*16+h)*64+d][4096]  (reused as kvT)
//   xb     @ 100663296  33.55MB  bf16 [16384][1024]   (kv f32 4MB overlays after K1)
//   Wqkvb  @ 134217728   6.29MB  bf16 [3072][1024]
//   Wob    @ 140509184   2.10MB  bf16 [1024][1024]
//   projT  @ 142606336   16KB    bf16 [128 m][64 d]
// total ~136MB.

typedef __attribute__((ext_vector_type(8))) short s8v;   // 8 x bf16 (16B)
typedef __attribute__((ext_vector_type(4))) short s4v;   // 4 x bf16 (8B)
typedef __attribute__((ext_vector_type(4))) float f32x4; // MFMA acc

#define MFMA_BF16(a, b, c) __builtin_amdgcn_mfma_f32_16x16x32_bf16((a), (b), (c), 0, 0, 0)

#define P_SCALE 0.125f                 // 1/sqrt(64)
#define F_SCALE 0.08838834764831845f   // 1/sqrt(128)

static __device__ __forceinline__ unsigned short f2bf(float f) {
  unsigned int u = __float_as_uint(f);
  u += 0x7fffu + ((u >> 16) & 1u);  // RNE
  return (unsigned short)(u >> 16);
}

// async 16B global->LDS (DMA; LDS dest = wave-uniform base + lane*16)
static __device__ __forceinline__ void gload_lds16(const void* g, void* l) {
  __builtin_amdgcn_global_load_lds(
      (const __attribute__((address_space(1))) unsigned int*)g,
      (__attribute__((address_space(3))) unsigned int*)l, 16, 0, 0);
}

// ---------------------------------------------------------------------------
// K0a: fp32 -> bf16 elementwise convert
// ---------------------------------------------------------------------------
__global__ void conv_bf16_kernel(const float* __restrict__ src, short* __restrict__ dst, int n) {
  int i4 = (blockIdx.x * 256 + threadIdx.x) * 4;
  if (i4 < n) {
    float4 f = *(const float4*)(src + i4);
    s4v v;
    v[0] = (short)f2bf(f.x); v[1] = (short)f2bf(f.y);
    v[2] = (short)f2bf(f.z); v[3] = (short)f2bf(f.w);
    *(s4v*)(dst + i4) = v;
  }
}

// K0b: proj [64][128] f32 -> projT [128][64] bf16
__global__ void projT_kernel(const float* __restrict__ proj, short* __restrict__ projT) {
  int t = threadIdx.x;
#pragma unroll
  for (int i = 0; i < 32; ++i) {
    int idx = t + i * 256;
    int d = idx >> 7, m = idx & 127;
    projT[m * 64 + d] = (short)f2bf(proj[idx]);
  }
}

// ---------------------------------------------------------------------------
// K1: qkv = xb @ Wqkv^T + bias. 128x128 tile, BK=64, bf16 MFMA,
// global_load_lds staging with XOR chunk swizzle.
// grid (128 row-tiles, 24 col-tiles). bn 0-7: q, 8-15: k, 16-23: v.
// ---------------------------------------------------------------------------
__global__ void qkv_gemm_kernel(const short* __restrict__ xb,
                                const short* __restrict__ Wqkv,
                                const float* __restrict__ bq_, const float* __restrict__ bk_,
                                const float* __restrict__ bv_,
                                short* __restrict__ qb, short* __restrict__ kb,
                                short* __restrict__ vT) {
  __shared__ __align__(16) short smem[17408];  // A[128][64]+B[128][64]; epi image [128][136]
  short* Al = smem;
  short* Bl = smem + 8192;

  const int t = threadIdx.x;
  const int bm = blockIdx.x, bn = blockIdx.y;
  const int row0 = bm * 128, n0 = bn * 128;
  const int lane = t & 63, w = t >> 6;
  const int wm = w & 1, wn = w >> 1;
  const int l15 = lane & 15, lq = lane >> 4;
  const int sx = (l15 & 7) * 8;   // fragment-read swizzle term (in shorts)

  f32x4 acc[4][4];
#pragma unroll
  for (int i = 0; i < 4; ++i)
#pragma unroll
    for (int j = 0; j < 4; ++j) acc[i][j] = (f32x4){0.f, 0.f, 0.f, 0.f};

  for (int k0 = 0; k0 < 1024; k0 += 64) {
#pragma unroll
    for (int i = 0; i < 4; ++i) {
      int c = t + i * 256;                 // chunk 0..1023
      int r = c >> 3, cl = c & 7;
      int cg = cl ^ (r & 7);               // permuted global chunk
      gload_lds16(xb   + (size_t)(row0 + r) * 1024 + k0 + cg * 8, Al + c * 8);
      gload_lds16(Wqkv + (size_t)(n0 + r) * 1024 + k0 + cg * 8, Bl + c * 8);
    }
    __syncthreads();
#pragma unroll
    for (int ks = 0; ks < 2; ++ks) {
      const int kb8 = (ks * 4 + lq) * 8;
      s8v af[4], bfr[4];
#pragma unroll
      for (int i = 0; i < 4; ++i)
        af[i] = *(s8v*)&Al[(wm * 64 + i * 16 + l15) * 64 + (kb8 ^ sx)];
#pragma unroll
      for (int j = 0; j < 4; ++j)
        bfr[j] = *(s8v*)&Bl[(wn * 64 + j * 16 + l15) * 64 + (kb8 ^ sx)];
#pragma unroll
      for (int i = 0; i < 4; ++i)
#pragma unroll
        for (int j = 0; j < 4; ++j)
          acc[i][j] = MFMA_BF16(af[i], bfr[j], acc[i][j]);
    }
    __syncthreads();
  }

  const int region = bn >> 3;  // 0 q, 1 k, 2 v
  if (region < 2) {
    const float* bias = (region == 0) ? bq_ : bk_;
    short* IM = smem;  // [128][136] natural image
#pragma unroll
    for (int j = 0; j < 4; ++j) {
      int cl = wn * 64 + j * 16 + l15;
      float bsv = bias[(n0 & 1023) + cl];
#pragma unroll
      for (int i = 0; i < 4; ++i)
#pragma unroll
        for (int r = 0; r < 4; ++r)
          IM[(wm * 64 + i * 16 + lq * 4 + r) * 136 + cl] = (short)f2bf(acc[i][j][r] + bsv);
    }
    __syncthreads();
    short* dst = (region == 0) ? qb : kb;
#pragma unroll
    for (int i = 0; i < 8; ++i) {
      int c = t + i * 256;
      int r = c >> 4, cc = c & 15;
      *(s8v*)&dst[(size_t)(row0 + r) * 1024 + (n0 & 1023) + cc * 8] =
          *(s8v*)&IM[r * 136 + cc * 8];
    }
  } else {
    short* IM = smem;  // [128 col][136] transposed image
#pragma unroll
    for (int j = 0; j < 4; ++j) {
      int cl = wn * 64 + j * 16 + l15;
      float bsv = bv_[(n0 - 2048) + cl];
#pragma unroll
      for (int i = 0; i < 4; ++i) {
        s4v pk;
#pragma unroll
        for (int r = 0; r < 4; ++r) pk[r] = (short)f2bf(acc[i][j][r] + bsv);
        *(s4v*)&IM[cl * 136 + wm * 64 + i * 16 + lq * 4] = pk;
      }
    }
    __syncthreads();
    const int b = row0 >> 12;
    const int l0 = (bm & 31) * 128;
#pragma unroll
    for (int i = 0; i < 8; ++i) {
      int c = t + i * 256;
      int ci = c >> 4, cc = c & 15;
      int cv = (bn - 16) * 128 + ci;      // 0..1023
      int grow = (b * 16 + (cv >> 6)) * 64 + (cv & 63);
      *(s8v*)&vT[(size_t)grow * 4096 + l0 + cc * 8] = *(s8v*)&IM[ci * 136 + cc * 8];
    }
  }
}

// ---------------------------------------------------------------------------
// K2: per (b,h,512-row chunk): fourier(k) -> k' ; kv += k'^T @ v  (MFMA),
// atomicAdd f32 flush. grid 512.
// ---------------------------------------------------------------------------
__global__ void kv_accum_kernel(const short* __restrict__ kb, const short* __restrict__ vT,
                                const short* __restrict__ projT, float* __restrict__ kv) {
  __shared__ __align__(16) short smem[26624];  // kt[64][64]+vt[64][64]+kpT[256][72]
  short* kt = smem;
  short* vt = smem + 4096;
  short* kpT = smem + 8192;

  const int t = threadIdx.x;
  const int bid = blockIdx.x;
  const int chunk = bid & 7, h = (bid >> 3) & 15, b = bid >> 7;
  const int lane = t & 63, w = t >> 6;
  const int l15 = lane & 15, lq = lane >> 4;
  const int sx = (l15 & 7) * 8;

  s8v pf[8][2];
#pragma unroll
  for (int nt = 0; nt < 8; ++nt)
#pragma unroll
    for (int ks = 0; ks < 2; ++ks)
      pf[nt][ks] = *(const s8v*)(projT + (size_t)(nt * 16 + l15) * 64 + ks * 32 + lq * 8);

  f32x4 kvacc[4][4];
#pragma unroll
  for (int i = 0; i < 4; ++i)
#pragma unroll
    for (int j = 0; j < 4; ++j) kvacc[i][j] = (f32x4){0.f, 0.f, 0.f, 0.f};

  for (int s = 0; s < 8; ++s) {
    const int l0s = chunk * 512 + s * 64;
#pragma unroll
    for (int i = 0; i < 2; ++i) {
      int c = t + i * 256;                 // chunk 0..511
      int r = c >> 3, cl = c & 7;
      int cg = cl ^ (r & 7);
      gload_lds16(kb + (size_t)(b * 4096 + l0s + r) * 1024 + h * 64 + cg * 8, kt + c * 8);
      gload_lds16(vT + (size_t)((b * 16 + h) * 64 + r) * 4096 + l0s + cg * 8, vt + c * 8);
    }
    __syncthreads();

    // fourier: wave w rows w*16..+15
    f32x4 pacc[8];
#pragma unroll
    for (int nt = 0; nt < 8; ++nt) pacc[nt] = (f32x4){0.f, 0.f, 0.f, 0.f};
#pragma unroll
    for (int ks = 0; ks < 2; ++ks) {
      const int kb8 = (ks * 4 + lq) * 8;
      s8v af = *(s8v*)&kt[(w * 16 + l15) * 64 + (kb8 ^ sx)];
#pragma unroll
      for (int nt = 0; nt < 8; ++nt) pacc[nt] = MFMA_BF16(af, pf[nt][ks], pacc[nt]);
    }
#pragma unroll
    for (int nt = 0; nt < 8; ++nt) {
      s4v cp, sp;
#pragma unroll
      for (int r = 0; r < 4; ++r) {
        float p = pacc[nt][r] * P_SCALE;
        float sv, cv;
        __sincosf(p, &sv, &cv);
        cp[r] = (short)f2bf(cv * F_SCALE);
        sp[r] = (short)f2bf(sv * F_SCALE);
      }
      int m = nt * 16 + l15;
      int rbase = w * 16 + lq * 4;
      *(s4v*)&kpT[m * 72 + rbase] = cp;
      *(s4v*)&kpT[(m + 128) * 72 + rbase] = sp;
    }
    __syncthreads();

    // kv MFMA: wave w m-range w*64..+63
#pragma unroll
    for (int ks = 0; ks < 2; ++ks) {
      const int kb8 = (ks * 4 + lq) * 8;
      s8v af[4], bf4[4];
#pragma unroll
      for (int i = 0; i < 4; ++i)
        af[i] = *(s8v*)&kpT[(w * 64 + i * 16 + l15) * 72 + ks * 32 + lq * 8];
#pragma unroll
      for (int j = 0; j < 4; ++j)
        bf4[j] = *(s8v*)&vt[(j * 16 + l15) * 64 + (kb8 ^ sx)];
#pragma unroll
      for (int i = 0; i < 4; ++i)
#pragma unroll
        for (int j = 0; j < 4; ++j)
          kvacc[i][j] = MFMA_BF16(af[i], bf4[j], kvacc[i][j]);
    }
    __syncthreads();
  }

  float* kvb = kv + ((size_t)(b * 16 + h) << 14);
#pragma unroll
  for (int i = 0; i < 4; ++i)
#pragma unroll
    for (int j = 0; j < 4; ++j)
#pragma unroll
      for (int r = 0; r < 4; ++r) {
        int m = w * 64 + i * 16 + lq * 4 + r;
        int d = j * 16 + l15;
        atomicAdd(kvb + (size_t)m * 64 + d, kvacc[i][j][r]);
      }
}

// ---------------------------------------------------------------------------
// K2.5: kv f32 [bh][256][64] -> kvT bf16 [bh*64+d][256]. grid 64.
// ---------------------------------------------------------------------------
__global__ void kvT_kernel(const float* __restrict__ kv, short* __restrict__ kvT) {
  __shared__ short im[16896];  // [64][264]
  const int t = threadIdx.x;
  const int bh = blockIdx.x;
  const float* src = kv + ((size_t)bh << 14);
#pragma unroll
  for (int i = 0; i < 64; ++i) {
    int idx = t + i * 256;
    int m = idx >> 6, d = idx & 63;
    im[d * 264 + m] = (short)f2bf(src[idx]);
  }
  __syncthreads();
#pragma unroll
  for (int i = 0; i < 8; ++i) {
    int c = t + i * 256;
    int d = c >> 5, cc = c & 31;
    *(s8v*)&kvT[(size_t)(bh * 64 + d) * 256 + cc * 8] = *(s8v*)&im[d * 264 + cc * 8];
  }
}

// ---------------------------------------------------------------------------
// K3: fourier(q) + attn = q' @ kv, per (64-row tile, head). grid (256,16).
// ---------------------------------------------------------------------------
__global__ void attn_kernel(const short* __restrict__ qb, const short* __restrict__ projT,
                            const short* __restrict__ kvT, short* __restrict__ attnb) {
  __shared__ __align__(16) short smem[20992];  // qt[64][64]+qA[64][136]+kvt[64][128]
  short* qt = smem;
  short* qA = smem + 4096;
  short* kvt = smem + 12800;

  const int t = threadIdx.x;
  const int rt = blockIdx.x, h = blockIdx.y;
  const int row0 = rt * 64;
  const int b = row0 >> 12;
  const int lane = t & 63, w = t >> 6;
  const int l15 = lane & 15, lq = lane >> 4;
  const int sx = (l15 & 7) * 8;

  s8v pf[8][2];
#pragma unroll
  for (int nt = 0; nt < 8; ++nt)
#pragma unroll
    for (int ks = 0; ks < 2; ++ks)
      pf[nt][ks] = *(const s8v*)(projT + (size_t)(nt * 16 + l15) * 64 + ks * 32 + lq * 8);

#pragma unroll
  for (int i = 0; i < 2; ++i) {
    int c = t + i * 256;
    int r = c >> 3, cl = c & 7;
    int cg = cl ^ (r & 7);
    gload_lds16(qb + (size_t)(row0 + r) * 1024 + h * 64 + cg * 8, qt + c * 8);
  }
  __syncthreads();

  f32x4 pacc[8];
#pragma unroll
  for (int nt = 0; nt < 8; ++nt) pacc[nt] = (f32x4){0.f, 0.f, 0.f, 0.f};
#pragma unroll
  for (int ks = 0; ks < 2; ++ks) {
    const int kb8 = (ks * 4 + lq) * 8;
    s8v af = *(s8v*)&qt[(w * 16 + l15) * 64 + (kb8 ^ sx)];
#pragma unroll
    for (int nt = 0; nt < 8; ++nt) pacc[nt] = MFMA_BF16(af, pf[nt][ks], pacc[nt]);
  }

  f32x4 aacc[4];
#pragma unroll
  for (int j = 0; j < 4; ++j) aacc[j] = (f32x4){0.f, 0.f, 0.f, 0.f};

#pragma unroll
  for (int half = 0; half < 2; ++half) {
    // q' half -> qA [64][136]
#pragma unroll
    for (int nt = 0; nt < 8; ++nt)
#pragma unroll
      for (int r = 0; r < 4; ++r) {
        float p = pacc[nt][r] * P_SCALE;
        float fv = (half == 0) ? __cosf(p) : __sinf(p);
        qA[(w * 16 + lq * 4 + r) * 136 + nt * 16 + l15] = (short)f2bf(fv * F_SCALE);
      }
    // stage kvT half: [64 d][128 m'], swizzled (16 chunks/row)
#pragma unroll
    for (int i = 0; i < 4; ++i) {
      int c = t + i * 256;                 // chunk 0..1023
      int d = c >> 4, cl = c & 15;
      int cg = cl ^ (d & 15);
      gload_lds16(kvT + (size_t)((b * 16 + h) * 64 + d) * 256 + half * 128 + cg * 8,
                  kvt + c * 8);
    }
    __syncthreads();
#pragma unroll
    for (int ks = 0; ks < 4; ++ks) {
      s8v af = *(s8v*)&qA[(w * 16 + l15) * 136 + ks * 32 + lq * 8];
#pragma unroll
      for (int j = 0; j < 4; ++j) {
        int row = j * 16 + l15;
        s8v bf4 = *(s8v*)&kvt[row * 128 + (((ks * 4 + lq) ^ l15) * 8)];
        aacc[j] = MFMA_BF16(af, bf4, aacc[j]);
      }
    }
    __syncthreads();
  }

  // epilogue image at smem base [64][72]
#pragma unroll
  for (int j = 0; j < 4; ++j)
#pragma unroll
    for (int r = 0; r < 4; ++r)
      smem[(w * 16 + lq * 4 + r) * 72 + j * 16 + l15] = (short)f2bf(aacc[j][r]);
  __syncthreads();
#pragma unroll
  for (int i = 0; i < 2; ++i) {
    int c = t + i * 256;
    int r = c >> 3, cc = c & 7;
    *(s8v*)&attnb[(size_t)(row0 + r) * 1024 + h * 64 + cc * 8] = *(s8v*)&smem[r * 72 + cc * 8];
  }
}

// ---------------------------------------------------------------------------
// K4: out = attn @ Wo^T + bo. fp32 out. grid (128, 8).
// ---------------------------------------------------------------------------
__global__ void out_gemm_kernel(const short* __restrict__ attnb, const short* __restrict__ Wob,
                                const float* __restrict__ bo_, float* __restrict__ out) {
  __shared__ __align__(16) short smem[16384];
  short* Al = smem;
  short* Bl = smem + 8192;

  const int t = threadIdx.x;
  const int bm = blockIdx.x, bn = blockIdx.y;
  const int row0 = bm * 128, n0 = bn * 128;
  const int lane = t & 63, w = t >> 6;
  const int wm = w & 1, wn = w >> 1;
  const int l15 = lane & 15, lq = lane >> 4;
  const int sx = (l15 & 7) * 8;

  f32x4 acc[4][4];
#pragma unroll
  for (int i = 0; i < 4; ++i)
#pragma unroll
    for (int j = 0; j < 4; ++j) acc[i][j] = (f32x4){0.f, 0.f, 0.f, 0.f};

  for (int k0 = 0; k0 < 1024; k0 += 64) {
#pragma unroll
    for (int i = 0; i < 4; ++i) {
      int c = t + i * 256;
      int r = c >> 3, cl = c & 7;
      int cg = cl ^ (r & 7);
      gload_lds16(attnb + (size_t)(row0 + r) * 1024 + k0 + cg * 8, Al + c * 8);
      gload_lds16(Wob   + (size_t)(n0 + r) * 1024 + k0 + cg * 8, Bl + c * 8);
    }
    __syncthreads();
#pragma unroll
    for (int ks = 0; ks < 2; ++ks) {
      const int kb8 = (ks * 4 + lq) * 8;
      s8v af[4], bfr[4];
#pragma unroll
      for (int i = 0; i < 4; ++i)
        af[i] = *(s8v*)&Al[(wm * 64 + i * 16 + l15) * 64 + (kb8 ^ sx)];
#pragma unroll
      for (int j = 0; j < 4; ++j)
        bfr[j] = *(s8v*)&Bl[(wn * 64 + j * 16 + l15) * 64 + (kb8 ^ sx)];
#pragma unroll
      for (int i = 0; i < 4; ++i)
#pragma unroll
        for (int j = 0; j < 4; ++j)
          acc[i][j] = MFMA_BF16(af[i], bfr[j], acc[i][j]);
    }
    __syncthreads();
  }

#pragma unroll
  for (int j = 0; j < 4; ++j) {
    int cl = wn * 64 + j * 16 + l15;
    float bsv = bo_[n0 + cl];
#pragma unroll
    for (int i = 0; i < 4; ++i)
#pragma unroll
      for (int r = 0; r < 4; ++r)
        out[(size_t)(row0 + wm * 64 + i * 16 + lq * 4 + r) * 1024 + n0 + cl] =
            acc[i][j][r] + bsv;
  }
}

// ---------------------------------------------------------------------------
extern "C" void kernel_launch(void* const* d_in, const int* in_sizes, int n_in,
                              void* d_out, int out_size, void* d_ws, size_t ws_size,
                              hipStream_t stream) {
  const float* x    = (const float*)d_in[0];
  const float* proj = (const float*)d_in[1];
  const float* Wq   = (const float*)d_in[2];
  const float* bq   = (const float*)d_in[3];
  const float* Wk   = (const float*)d_in[4];
  const float* bk   = (const float*)d_in[5];
  const float* Wv   = (const float*)d_in[6];
  const float* bv   = (const float*)d_in[7];
  const float* Wo   = (const float*)d_in[8];
  const float* bo   = (const float*)d_in[9];
  float* out = (float*)d_out;

  char* wsb = (char*)d_ws;
  short* qb    = (short*)(wsb + 0);
  short* kb    = (short*)(wsb + 33554432);
  short* vT    = (short*)(wsb + 67108864);
  short* xb    = (short*)(wsb + 100663296);
  short* Wqkvb = (short*)(wsb + 134217728);
  short* Wob   = (short*)(wsb + 140509184);
  short* projT = (short*)(wsb + 142606336);
  float* kv    = (float*)(wsb + 100663296);  // overlays xb (dead after K1)
  short* attnb = kb;                          // kb dead after K2
  short* kvT   = vT;                          // vT dead after K2

  const int WN = 1024 * 1024;
  conv_bf16_kernel<<<dim3(16384), dim3(256), 0, stream>>>(x, xb, 16777216);
  conv_bf16_kernel<<<dim3(WN / 1024), dim3(256), 0, stream>>>(Wq, Wqkvb, WN);
  conv_bf16_kernel<<<dim3(WN / 1024), dim3(256), 0, stream>>>(Wk, Wqkvb + WN, WN);
  conv_bf16_kernel<<<dim3(WN / 1024), dim3(256), 0, stream>>>(Wv, Wqkvb + 2 * WN, WN);
  conv_bf16_kernel<<<dim3(WN / 1024), dim3(256), 0, stream>>>(Wo, Wob, WN);
  projT_kernel<<<dim3(1), dim3(256), 0, stream>>>(proj, projT);

  qkv_gemm_kernel<<<dim3(128, 24), dim3(256), 0, stream>>>(x ? xb : xb, Wqkvb, bq, bk, bv, qb, kb, vT);
  hipMemsetAsync(kv, 0, 4194304, stream);   // after K1: kv overlays xb
  kv_accum_kernel<<<dim3(512), dim3(256), 0, stream>>>(kb, vT, projT, kv);
  kvT_kernel<<<dim3(64), dim3(256), 0, stream>>>(kv, kvT);
  attn_kernel<<<dim3(256, 16), dim3(256), 0, stream>>>(qb, projT, kvT, attnb);
  out_gemm_kernel<<<dim3(128, 8), dim3(256), 0, stream>>>(attnb, Wob, bo, out);
}